// Round 10
// baseline (485.673 us; speedup 1.0000x reference)
//
#include <hip/hip_runtime.h>
#include <math.h>

// ClownSelector R19: R18's 8tok x 8exp tile at 16 waves/CU (4 waves/SIMD).
//
// R18 post-mortem: tile worked (VGPR 116, conflicts low, no spill) but grid
// 256 x 8 waves = 2 waves/SIMD (Occ 17%) -> latency-exposed: VALU 33%,
// DS ~53%, neither saturated. R13 vs R18 = waves-without-lean-tile vs
// lean-tile-without-waves, both ~44us.
//
// R19: same tile, K split 16-way (64 k/wave), 1024-thr block, 256 blocks
// = 16 waves/CU = 4 waves/SIMD (the config that measured 38-40% occ in
// R15/R17). Per-CU DS (~24us) and VALU (~14us) totals unchanged from R18;
// doubled TLP overlaps them. 16-wave tree = R14's verified sequence.
// __launch_bounds__(1024) with NO second arg (R15/R17: need-based VGPR 28;
// R14's (1024,4) caused the 64-cap spill). Canary: WRITE_SIZE >> 4MB.
// top2 (oct-per-thread) + repack: R17/R18 verbatim.

#define BB 8
#define SS 2048
#define DD 1024
#define EE 64
#define EPSV 1e-8f

#define FMA4(A, s, P) \
  A.x += (s) * (P).x; A.y += (s) * (P).y; A.z += (s) * (P).z; A.w += (s) * (P).w;

#define SUMSQ4(v) ((v).x * (v).x + (v).y * (v).y + (v).z * (v).z + (v).w * (v).w)

// ---- K0: proto[e][d] -> ptt[d][e] -----------------------------------------
__global__ __launch_bounds__(256) void repack_proto(
    const float* __restrict__ proto, float* __restrict__ ptt) {
  const int gid = blockIdx.x * 256 + threadIdx.x;  // 0..65535
  const int d = gid >> 6;
  const int e = gid & 63;
  ptt[gid] = proto[(size_t)e * DD + d];
}

// ---- K1: normalized per-row dots ------------------------------------------
// SMEM layout (floats):
//   [    0 ..  8703]  xt: 16 waves x [8 k][68 pad]   (single-buffered)
//   [ 8704 .. 16895]  pt: 16 waves x [8 k][64 e]     (single-buffered)
//   [16896 .. 17919]  nq: [16 wave][64 tok]
// Epilogue aliases B0 = SMEM[0..4351], B1 = SMEM[4352..8703] (dead xt).
__global__ __launch_bounds__(1024) void router_dots(
    const float* __restrict__ x, const float* __restrict__ ptt,
    float* __restrict__ dots) {
  __shared__ float SMEM[17920];

  const int tid  = threadIdx.x;
  const int lane = tid & 63;
  const int w    = __builtin_amdgcn_readfirstlane(tid >> 6);  // 0..15
  const int eg   = lane & 7;   // experts [eg*8, +8)
  const int tg   = lane >> 3;  // tokens  [tg*8, +8)
  const int b    = blockIdx.x >> 5;          // 8 batches
  const int s0   = (blockIdx.x & 31) * 64;   // 64 tokens per block

  float* xtw = SMEM + w * 544;            // [8][68]
  float* ptw = SMEM + 8704 + w * 512;     // [8][64]
  float* nqp = SMEM + 16896;              // [16][64]

  const int kbase = w * 64;   // this wave's k-slice (64 wide)
  // staging sources: lane stages token `lane` (x) / 4 floats (proto)
  const float* xsrow = x + ((size_t)b * SS + s0 + lane) * DD + kbase;
  const float* psrow = ptt + (size_t)kbase * EE + lane * 4;

  float4 accA0[4], accA1[4], accB0[4], accB1[4];
#pragma unroll
  for (int i = 0; i < 4; ++i) {
    accA0[i] = make_float4(0.f, 0.f, 0.f, 0.f);
    accA1[i] = make_float4(0.f, 0.f, 0.f, 0.f);
    accB0[i] = make_float4(0.f, 0.f, 0.f, 0.f);
    accB1[i] = make_float4(0.f, 0.f, 0.f, 0.f);
  }
  float q = 0.0f;

  // ---- prologue: stage chunk 0 (x transposed + proto) ----
  {
    const float4 v0 = *(const float4*)(xsrow);
    const float4 v1 = *(const float4*)(xsrow + 4);
    const float4 r0 = *(const float4*)(psrow);
    const float4 r1 = *(const float4*)(psrow + 256);
    q += SUMSQ4(v0) + SUMSQ4(v1);
    float* d = xtw + lane;
    d[0]   = v0.x; d[68]  = v0.y; d[136] = v0.z; d[204] = v0.w;
    d[272] = v1.x; d[340] = v1.y; d[408] = v1.z; d[476] = v1.w;
    *(float4*)(ptw + lane * 4)       = r0;
    *(float4*)(ptw + 256 + lane * 4) = r1;
  }

  const float* xc = xtw + tg * 8;   // + kk*68
  const float* pc = ptw + eg * 8;   // + kk*64

  for (int c = 0; c < 8; ++c) {   // 8 chunks x 8 k = 64 k per wave
    // ---- prefetch next chunk (consumed after the k-loop) ----
    float4 v0, v1, r0, r1;
    if (c + 1 < 8) {
      v0 = *(const float4*)(xsrow + (c + 1) * 8);
      v1 = *(const float4*)(xsrow + (c + 1) * 8 + 4);
      r0 = *(const float4*)(psrow + (c + 1) * 512);
      r1 = *(const float4*)(psrow + (c + 1) * 512 + 256);
    }
    // ---- 8 k-steps: 2 b128 (x, 8 tok) + 2 b128 (proto, 8 exp) + 64 fmac ----
#pragma unroll
    for (int kk = 0; kk < 8; ++kk) {
      const float4 xfA = *(const float4*)(xc + kk * 68);
      const float4 xfB = *(const float4*)(xc + kk * 68 + 4);
      const float4 p0  = *(const float4*)(pc + kk * 64);
      const float4 p1  = *(const float4*)(pc + kk * 64 + 4);
      FMA4(accA0[0], xfA.x, p0) FMA4(accA1[0], xfA.x, p1)
      FMA4(accA0[1], xfA.y, p0) FMA4(accA1[1], xfA.y, p1)
      FMA4(accA0[2], xfA.z, p0) FMA4(accA1[2], xfA.z, p1)
      FMA4(accA0[3], xfA.w, p0) FMA4(accA1[3], xfA.w, p1)
      FMA4(accB0[0], xfB.x, p0) FMA4(accB1[0], xfB.x, p1)
      FMA4(accB0[1], xfB.y, p0) FMA4(accB1[1], xfB.y, p1)
      FMA4(accB0[2], xfB.z, p0) FMA4(accB1[2], xfB.z, p1)
      FMA4(accB0[3], xfB.w, p0) FMA4(accB1[3], xfB.w, p1)
    }
    // ---- stage prefetched chunk (same buffers; wave-private DS in-order) ----
    if (c + 1 < 8) {
      q += SUMSQ4(v0) + SUMSQ4(v1);
      float* d = xtw + lane;
      d[0]   = v0.x; d[68]  = v0.y; d[136] = v0.z; d[204] = v0.w;
      d[272] = v1.x; d[340] = v1.y; d[408] = v1.z; d[476] = v1.w;
      *(float4*)(ptw + lane * 4)       = r0;
      *(float4*)(ptw + 256 + lane * 4) = r1;
    }
  }

  // per-token (lane) sumsq partial for this wave's 64-k slice
  nqp[w * 64 + lane] = q;

  // epilogue tree buffers alias the (now dead) xt region: [64][68]
  float* B0 = SMEM;
  float* B1 = SMEM + 4352;

#define WRB(R)                                                        \
  { _Pragma("unroll") for (int i = 0; i < 4; ++i) {                   \
      float* pA_ = (R) + (tg * 8 + i) * 68 + eg * 8;                  \
      float* pB_ = (R) + (tg * 8 + 4 + i) * 68 + eg * 8;              \
      *(float4*)(pA_)     = accA0[i];                                 \
      *(float4*)(pA_ + 4) = accA1[i];                                 \
      *(float4*)(pB_)     = accB0[i];                                 \
      *(float4*)(pB_ + 4) = accB1[i]; } }
#define ADDB(R)                                                       \
  { _Pragma("unroll") for (int i = 0; i < 4; ++i) {                   \
      const float* pA_ = (R) + (tg * 8 + i) * 68 + eg * 8;            \
      const float* pB_ = (R) + (tg * 8 + 4 + i) * 68 + eg * 8;        \
      const float4 tA0 = *(const float4*)(pA_);                       \
      const float4 tA1 = *(const float4*)(pA_ + 4);                   \
      const float4 tB0 = *(const float4*)(pB_);                       \
      const float4 tB1 = *(const float4*)(pB_ + 4);                   \
      accA0[i].x += tA0.x; accA0[i].y += tA0.y;                       \
      accA0[i].z += tA0.z; accA0[i].w += tA0.w;                       \
      accA1[i].x += tA1.x; accA1[i].y += tA1.y;                       \
      accA1[i].z += tA1.z; accA1[i].w += tA1.w;                       \
      accB0[i].x += tB0.x; accB0[i].y += tB0.y;                       \
      accB0[i].z += tB0.z; accB0[i].w += tB0.w;                       \
      accB1[i].x += tB1.x; accB1[i].y += tB1.y;                       \
      accB1[i].z += tB1.z; accB1[i].w += tB1.w; } }

  // deterministic pairwise tree over 16 waves (R14's verified sequence)
  __syncthreads();
  if (w == 1) WRB(B0)   if (w == 5) WRB(B1)
  __syncthreads();
  if (w == 0) ADDB(B0)  if (w == 4) ADDB(B1)
  __syncthreads();
  if (w == 3) WRB(B0)   if (w == 7) WRB(B1)
  __syncthreads();
  if (w == 2) ADDB(B0)  if (w == 6) ADDB(B1)
  __syncthreads();
  if (w == 9) WRB(B0)   if (w == 13) WRB(B1)
  __syncthreads();
  if (w == 8) ADDB(B0)  if (w == 12) ADDB(B1)
  __syncthreads();
  if (w == 11) WRB(B0)  if (w == 15) WRB(B1)
  __syncthreads();
  if (w == 10) ADDB(B0) if (w == 14) ADDB(B1)
  __syncthreads();
  if (w == 2) WRB(B0)   if (w == 6) WRB(B1)
  __syncthreads();
  if (w == 0) ADDB(B0)  if (w == 4) ADDB(B1)
  __syncthreads();
  if (w == 10) WRB(B0)  if (w == 14) WRB(B1)
  __syncthreads();
  if (w == 8) ADDB(B0)  if (w == 12) ADDB(B1)
  __syncthreads();
  if (w == 4) WRB(B0)   if (w == 12) WRB(B1)
  __syncthreads();
  if (w == 0) ADDB(B0)  if (w == 8) ADDB(B1)
  __syncthreads();
  if (w == 8) WRB(B0)
  __syncthreads();
  if (w == 0) {
    ADDB(B0)
#pragma unroll
    for (int i = 0; i < 4; ++i) {
      const int rA = tg * 8 + i;
      const int rB = rA + 4;
      float qsA = 0.0f, qsB = 0.0f;
#pragma unroll
      for (int ww = 0; ww < 16; ++ww) {
        qsA += nqp[ww * 64 + rA];
        qsB += nqp[ww * 64 + rB];
      }
      const float invA = 1.0f / fmaxf(sqrtf(qsA), EPSV);
      const float invB = 1.0f / fmaxf(sqrtf(qsB), EPSV);
      float4 oA0 = accA0[i], oA1 = accA1[i], oB0 = accB0[i], oB1 = accB1[i];
      oA0.x *= invA; oA0.y *= invA; oA0.z *= invA; oA0.w *= invA;
      oA1.x *= invA; oA1.y *= invA; oA1.z *= invA; oA1.w *= invA;
      oB0.x *= invB; oB0.y *= invB; oB0.z *= invB; oB0.w *= invB;
      oB1.x *= invB; oB1.y *= invB; oB1.z *= invB; oB1.w *= invB;
      float* dpA = dots + ((size_t)b * SS + s0 + rA) * EE + eg * 8;
      float* dpB = dots + ((size_t)b * SS + s0 + rB) * EE + eg * 8;
      *(float4*)(dpA)     = oA0;
      *(float4*)(dpA + 4) = oA1;
      *(float4*)(dpB)     = oB0;
      *(float4*)(dpB + 4) = oB1;
    }
  }
}

// ---- K2: window-3 + top-2 + renorm softmax, oct-per-thread (R17) -----------
#define T2UP(s, ei)                                            \
  if ((s) > v1) { v2 = v1; i2 = i1; v1 = (s); i1 = (ei); }     \
  else if ((s) > v2) { v2 = (s); i2 = (ei); }

__global__ __launch_bounds__(256) void router_top2(
    const float* __restrict__ dots, float* __restrict__ out) {
  const int gtid = blockIdx.x * 256 + threadIdx.x;  // 0..131071
  const int tok  = gtid >> 3;          // global token
  const int h    = gtid & 7;           // expert oct (8 experts each)
  const int b    = tok >> 11;
  const int sl   = tok & (SS - 1);
  const int r0   = (sl >= 2) ? sl - 2 : 0;   // causal pad: replicate token 0
  const int r1   = (sl >= 1) ? sl - 1 : 0;

  const float* d0 = dots + ((size_t)b * SS + r0) * EE + h * 8;
  const float* d1 = dots + ((size_t)b * SS + r1) * EE + h * 8;
  const float* d2 = dots + ((size_t)b * SS + sl) * EE + h * 8;

  float v1 = -INFINITY, v2 = -INFINITY;
  int i1 = 0, i2 = 0;
#pragma unroll
  for (int qd = 0; qd < 2; ++qd) {
    const float4 a = *(const float4*)(d0 + qd * 4);
    const float4 c = *(const float4*)(d1 + qd * 4);
    const float4 e = *(const float4*)(d2 + qd * 4);
    const int e0 = h * 8 + qd * 4;
    float s;
    s = a.x + c.x + e.x; T2UP(s, e0 + 0)
    s = a.y + c.y + e.y; T2UP(s, e0 + 1)
    s = a.z + c.z + e.z; T2UP(s, e0 + 2)
    s = a.w + c.w + e.w; T2UP(s, e0 + 3)
  }

  // merge the 8 octs (partners lane^1, lane^2, lane^4); tie -> lower index
#pragma unroll
  for (int m = 1; m <= 4; m <<= 1) {
    const float ov1 = __shfl_xor(v1, m);
    const int   oi1 = __shfl_xor(i1, m);
    const float ov2 = __shfl_xor(v2, m);
    const int   oi2 = __shfl_xor(i2, m);
    const bool o_beats = (ov1 > v1) || (ov1 == v1 && oi1 < i1);
    if (o_beats) {
      const bool v1_beats_o2 = (v1 > ov2) || (v1 == ov2 && i1 < oi2);
      v2 = v1_beats_o2 ? v1 : ov2;
      i2 = v1_beats_o2 ? i1 : oi2;
      v1 = ov1;
      i1 = oi1;
    } else {
      const bool o1_beats_v2 = (ov1 > v2) || (ov1 == v2 && oi1 < i2);
      if (o1_beats_v2) { v2 = ov1; i2 = oi1; }
    }
  }

  if (h == 0) {
    const float ex = expf((v2 - v1) * (1.0f / 3.0f));  // <= 1
    const float w1 = 1.0f / (1.0f + ex);
    const size_t o = (size_t)tok * 2;
    *(float2*)(out + o) = make_float2((float)i1, (float)i2);
    *(float2*)(out + (size_t)BB * SS * 2 + o) = make_float2(w1, ex * w1);
  }
}

extern "C" void kernel_launch(void* const* d_in, const int* in_sizes, int n_in,
                              void* d_out, int out_size, void* d_ws, size_t ws_size,
                              hipStream_t stream) {
  const float* x     = (const float*)d_in[0];
  const float* proto = (const float*)d_in[1];
  // d_in[2] = attn_mask: unused by the reference output path.
  float* out  = (float*)d_out;
  float* ptt  = (float*)d_ws;                          // 256 KiB ptt[d][e]
  float* dots = (float*)((char*)d_ws + (512 << 10));   // 4 MiB normalized dots

  repack_proto<<<dim3(256), dim3(256), 0, stream>>>(proto, ptt);
  router_dots<<<dim3(256), dim3(1024), 0, stream>>>(x, ptt, dots);
  router_top2<<<dim3(512), dim3(256), 0, stream>>>(dots, out);
}

// Round 11
// 146.183 us; speedup vs baseline: 3.3224x; 3.3224x over previous
//
#include <hip/hip_runtime.h>
#include <math.h>

// ClownSelector R20: R18 tile + split-K over 2 blocks -> 4 waves/SIMD.
//
// R19 post-mortem: 1024-thread blocks are HARD-CAPPED at 64 VGPR by hipcc
// (R14 and R19 both measured 64; launch_bounds arg irrelevant). The
// 116-VGPR tile spilled -> 429us. Rule: this tile needs 512-thr blocks.
//
// R18 proved the 8tok x 8exp tile (DS/CU ~20.5us vs VALU 13.7us) but at
// grid 256 = 1 block/CU = 2 waves/SIMD it is latency-exposed (Occ 17%,
// 45us). 4 waves/SIMD with 512-thr blocks needs grid 512: split K 2-way
// across blocks. Each block: UNNORMALIZED half-K (512 k) partial dots +
// partial sumsq (R18's staging/tile/tree verbatim, 8 chunks not 16).
// top2 combines: n = (p0+p1)*rsqrt(q0+q1) per row, then the verified
// window-3 / top-2 / softmax. Normalization is per source row, so it
// commutes with the window sum exactly as before; only fp association
// changes (R13->R15->R18 order changes all passed, absmax 0).
// Workspace: ptt 256KB @0; pdots 2x4MB @512KB; qpart 2x64KB @512KB+8MB.
// Canary: VGPR must be ~116 (not 64); WRITE_SIZE ~8.3MB legit, >>12 = spill.

#define BB 8
#define SS 2048
#define DD 1024
#define EE 64
#define EPSV 1e-8f

#define FMA4(A, s, P) \
  A.x += (s) * (P).x; A.y += (s) * (P).y; A.z += (s) * (P).z; A.w += (s) * (P).w;

#define SUMSQ4(v) ((v).x * (v).x + (v).y * (v).y + (v).z * (v).z + (v).w * (v).w)

// ---- K0: proto[e][d] -> ptt[d][e] -----------------------------------------
__global__ __launch_bounds__(256) void repack_proto(
    const float* __restrict__ proto, float* __restrict__ ptt) {
  const int gid = blockIdx.x * 256 + threadIdx.x;  // 0..65535
  const int d = gid >> 6;
  const int e = gid & 63;
  ptt[gid] = proto[(size_t)e * DD + d];
}

// ---- K1: half-K unnormalized partial dots ----------------------------------
// grid 512 = (256 token-blocks) x (2 K-halves). 512 thr = 8 waves, each a
// 64-k slice of this block's 512-k half. SMEM geometry = R18 verbatim:
//   [   0 .. 4351]  xt: 8 waves x [8 k][68 pad]   (single-buffered)
//   [4352 .. 8447]  pt: 8 waves x [8 k][64 e]     (single-buffered)
//   [8704 .. 9215]  nq: [8 wave][64 tok]
// Epilogue aliases B0 = SMEM[0..4351], B1 = SMEM[4352..8703].
__global__ __launch_bounds__(512) void router_dots(
    const float* __restrict__ x, const float* __restrict__ ptt,
    float* __restrict__ pdots, float* __restrict__ qpart) {
  __shared__ float SMEM[9216];

  const int tid  = threadIdx.x;
  const int lane = tid & 63;
  const int w    = __builtin_amdgcn_readfirstlane(tid >> 6);  // 0..7
  const int eg   = lane & 7;   // experts [eg*8, +8)
  const int tg   = lane >> 3;  // tokens  [tg*8, +8)
  const int hb   = blockIdx.x & 1;           // K half: [hb*512, +512)
  const int tb   = blockIdx.x >> 1;          // token block 0..255
  const int b    = tb >> 5;                  // 8 batches
  const int s0   = (tb & 31) * 64;           // 64 tokens per block

  float* xtw = SMEM + w * 544;           // [8][68]
  float* ptw = SMEM + 4352 + w * 512;    // [8][64]
  float* nqp = SMEM + 8704;              // [8][64]

  const int kbase = hb * 512 + w * 64;   // this wave's k-slice (64 wide)
  // staging sources: lane stages token `lane` (x) / 4 floats (proto)
  const float* xsrow = x + ((size_t)b * SS + s0 + lane) * DD + kbase;
  const float* psrow = ptt + (size_t)kbase * EE + lane * 4;

  float4 accA0[4], accA1[4], accB0[4], accB1[4];
#pragma unroll
  for (int i = 0; i < 4; ++i) {
    accA0[i] = make_float4(0.f, 0.f, 0.f, 0.f);
    accA1[i] = make_float4(0.f, 0.f, 0.f, 0.f);
    accB0[i] = make_float4(0.f, 0.f, 0.f, 0.f);
    accB1[i] = make_float4(0.f, 0.f, 0.f, 0.f);
  }
  float q = 0.0f;

  // ---- prologue: stage chunk 0 (x transposed + proto) ----
  {
    const float4 v0 = *(const float4*)(xsrow);
    const float4 v1 = *(const float4*)(xsrow + 4);
    const float4 r0 = *(const float4*)(psrow);
    const float4 r1 = *(const float4*)(psrow + 256);
    q += SUMSQ4(v0) + SUMSQ4(v1);
    float* d = xtw + lane;
    d[0]   = v0.x; d[68]  = v0.y; d[136] = v0.z; d[204] = v0.w;
    d[272] = v1.x; d[340] = v1.y; d[408] = v1.z; d[476] = v1.w;
    *(float4*)(ptw + lane * 4)       = r0;
    *(float4*)(ptw + 256 + lane * 4) = r1;
  }

  const float* xc = xtw + tg * 8;   // + kk*68
  const float* pc = ptw + eg * 8;   // + kk*64

  for (int c = 0; c < 8; ++c) {   // 8 chunks x 8 k = 64 k per wave
    // ---- prefetch next chunk (consumed after the k-loop) ----
    float4 v0, v1, r0, r1;
    if (c + 1 < 8) {
      v0 = *(const float4*)(xsrow + (c + 1) * 8);
      v1 = *(const float4*)(xsrow + (c + 1) * 8 + 4);
      r0 = *(const float4*)(psrow + (c + 1) * 512);
      r1 = *(const float4*)(psrow + (c + 1) * 512 + 256);
    }
    // ---- 8 k-steps: 2 b128 (x, 8 tok) + 2 b128 (proto, 8 exp) + 64 fmac ----
#pragma unroll
    for (int kk = 0; kk < 8; ++kk) {
      const float4 xfA = *(const float4*)(xc + kk * 68);
      const float4 xfB = *(const float4*)(xc + kk * 68 + 4);
      const float4 p0  = *(const float4*)(pc + kk * 64);
      const float4 p1  = *(const float4*)(pc + kk * 64 + 4);
      FMA4(accA0[0], xfA.x, p0) FMA4(accA1[0], xfA.x, p1)
      FMA4(accA0[1], xfA.y, p0) FMA4(accA1[1], xfA.y, p1)
      FMA4(accA0[2], xfA.z, p0) FMA4(accA1[2], xfA.z, p1)
      FMA4(accA0[3], xfA.w, p0) FMA4(accA1[3], xfA.w, p1)
      FMA4(accB0[0], xfB.x, p0) FMA4(accB1[0], xfB.x, p1)
      FMA4(accB0[1], xfB.y, p0) FMA4(accB1[1], xfB.y, p1)
      FMA4(accB0[2], xfB.z, p0) FMA4(accB1[2], xfB.z, p1)
      FMA4(accB0[3], xfB.w, p0) FMA4(accB1[3], xfB.w, p1)
    }
    // ---- stage prefetched chunk (same buffers; wave-private DS in-order) ----
    if (c + 1 < 8) {
      q += SUMSQ4(v0) + SUMSQ4(v1);
      float* d = xtw + lane;
      d[0]   = v0.x; d[68]  = v0.y; d[136] = v0.z; d[204] = v0.w;
      d[272] = v1.x; d[340] = v1.y; d[408] = v1.z; d[476] = v1.w;
      *(float4*)(ptw + lane * 4)       = r0;
      *(float4*)(ptw + 256 + lane * 4) = r1;
    }
  }

  // per-token (lane) sumsq partial for this wave's 64-k slice
  nqp[w * 64 + lane] = q;

  // epilogue tree buffers alias the (now dead) xt region: [64][68]
  float* B0 = SMEM;
  float* B1 = SMEM + 4352;

#define WRB(R)                                                        \
  { _Pragma("unroll") for (int i = 0; i < 4; ++i) {                   \
      float* pA_ = (R) + (tg * 8 + i) * 68 + eg * 8;                  \
      float* pB_ = (R) + (tg * 8 + 4 + i) * 68 + eg * 8;              \
      *(float4*)(pA_)     = accA0[i];                                 \
      *(float4*)(pA_ + 4) = accA1[i];                                 \
      *(float4*)(pB_)     = accB0[i];                                 \
      *(float4*)(pB_ + 4) = accB1[i]; } }
#define ADDB(R)                                                       \
  { _Pragma("unroll") for (int i = 0; i < 4; ++i) {                   \
      const float* pA_ = (R) + (tg * 8 + i) * 68 + eg * 8;            \
      const float* pB_ = (R) + (tg * 8 + 4 + i) * 68 + eg * 8;        \
      const float4 tA0 = *(const float4*)(pA_);                       \
      const float4 tA1 = *(const float4*)(pA_ + 4);                   \
      const float4 tB0 = *(const float4*)(pB_);                       \
      const float4 tB1 = *(const float4*)(pB_ + 4);                   \
      accA0[i].x += tA0.x; accA0[i].y += tA0.y;                       \
      accA0[i].z += tA0.z; accA0[i].w += tA0.w;                       \
      accA1[i].x += tA1.x; accA1[i].y += tA1.y;                       \
      accA1[i].z += tA1.z; accA1[i].w += tA1.w;                       \
      accB0[i].x += tB0.x; accB0[i].y += tB0.y;                       \
      accB0[i].z += tB0.z; accB0[i].w += tB0.w;                       \
      accB1[i].x += tB1.x; accB1[i].y += tB1.y;                       \
      accB1[i].z += tB1.z; accB1[i].w += tB1.w; } }

  // deterministic tree over 8 waves (R13/R18's exact sequence)
  __syncthreads();
  if (w == 1) WRB(B0)
  if (w == 5) WRB(B1)
  __syncthreads();
  if (w == 0) ADDB(B0)
  if (w == 4) ADDB(B1)
  __syncthreads();
  if (w == 3) WRB(B0)
  if (w == 7) WRB(B1)
  __syncthreads();
  if (w == 2) ADDB(B0)
  if (w == 6) ADDB(B1)
  __syncthreads();
  if (w == 2) WRB(B0)
  if (w == 6) WRB(B1)
  __syncthreads();
  if (w == 0) ADDB(B0)
  if (w == 4) ADDB(B1)
  __syncthreads();
  if (w == 4) WRB(B0)
  __syncthreads();
  if (w == 0) {
    ADDB(B0)
    const size_t half = (size_t)BB * SS * EE;
#pragma unroll
    for (int i = 0; i < 4; ++i) {
      const int rA = tg * 8 + i;
      const int rB = rA + 4;
      float* dpA = pdots + hb * half + ((size_t)b * SS + s0 + rA) * EE + eg * 8;
      float* dpB = pdots + hb * half + ((size_t)b * SS + s0 + rB) * EE + eg * 8;
      *(float4*)(dpA)     = accA0[i];
      *(float4*)(dpA + 4) = accA1[i];
      *(float4*)(dpB)     = accB0[i];
      *(float4*)(dpB + 4) = accB1[i];
    }
    if (eg == 0) {
#pragma unroll
      for (int i = 0; i < 4; ++i) {
        const int rA = tg * 8 + i;
        const int rB = rA + 4;
        float qsA = 0.0f, qsB = 0.0f;
#pragma unroll
        for (int ww = 0; ww < 8; ++ww) {
          qsA += nqp[ww * 64 + rA];
          qsB += nqp[ww * 64 + rB];
        }
        qpart[hb * (size_t)(BB * SS) + (size_t)b * SS + s0 + rA] = qsA;
        qpart[hb * (size_t)(BB * SS) + (size_t)b * SS + s0 + rB] = qsB;
      }
    }
  }
}

// ---- K2: combine halves + normalize + window-3 + top-2 + softmax -----------
#define T2UP(s, ei)                                            \
  if ((s) > v1) { v2 = v1; i2 = i1; v1 = (s); i1 = (ei); }     \
  else if ((s) > v2) { v2 = (s); i2 = (ei); }

__global__ __launch_bounds__(256) void router_top2(
    const float* __restrict__ pdots, const float* __restrict__ qpart,
    float* __restrict__ out) {
  const int gtid = blockIdx.x * 256 + threadIdx.x;  // 0..131071
  const int tok  = gtid >> 3;          // global token
  const int h    = gtid & 7;           // expert oct (8 experts each)
  const int b    = tok >> 11;
  const int sl   = tok & (SS - 1);
  const int r0   = (sl >= 2) ? sl - 2 : 0;   // causal pad: replicate token 0
  const int r1   = (sl >= 1) ? sl - 1 : 0;

  const size_t half = (size_t)BB * SS * EE;
  const size_t rb   = (size_t)b * SS;

  const float inv0 =
      1.0f / fmaxf(sqrtf(qpart[rb + r0] + qpart[(size_t)BB * SS + rb + r0]), EPSV);
  const float inv1 =
      1.0f / fmaxf(sqrtf(qpart[rb + r1] + qpart[(size_t)BB * SS + rb + r1]), EPSV);
  const float inv2 =
      1.0f / fmaxf(sqrtf(qpart[rb + sl] + qpart[(size_t)BB * SS + rb + sl]), EPSV);

  const float* a0 = pdots + (rb + r0) * EE + h * 8;
  const float* a1 = pdots + half + (rb + r0) * EE + h * 8;
  const float* c0 = pdots + (rb + r1) * EE + h * 8;
  const float* c1 = pdots + half + (rb + r1) * EE + h * 8;
  const float* e0p = pdots + (rb + sl) * EE + h * 8;
  const float* e1p = pdots + half + (rb + sl) * EE + h * 8;

  float v1 = -INFINITY, v2 = -INFINITY;
  int i1 = 0, i2 = 0;
#pragma unroll
  for (int qd = 0; qd < 2; ++qd) {
    const float4 aL = *(const float4*)(a0 + qd * 4);
    const float4 aH = *(const float4*)(a1 + qd * 4);
    const float4 cL = *(const float4*)(c0 + qd * 4);
    const float4 cH = *(const float4*)(c1 + qd * 4);
    const float4 eL = *(const float4*)(e0p + qd * 4);
    const float4 eH = *(const float4*)(e1p + qd * 4);
    const int ei = h * 8 + qd * 4;
    float s;
    s = (aL.x + aH.x) * inv0 + (cL.x + cH.x) * inv1 + (eL.x + eH.x) * inv2;
    T2UP(s, ei + 0)
    s = (aL.y + aH.y) * inv0 + (cL.y + cH.y) * inv1 + (eL.y + eH.y) * inv2;
    T2UP(s, ei + 1)
    s = (aL.z + aH.z) * inv0 + (cL.z + cH.z) * inv1 + (eL.z + eH.z) * inv2;
    T2UP(s, ei + 2)
    s = (aL.w + aH.w) * inv0 + (cL.w + cH.w) * inv1 + (eL.w + eH.w) * inv2;
    T2UP(s, ei + 3)
  }

  // merge the 8 octs (partners lane^1, lane^2, lane^4); tie -> lower index
#pragma unroll
  for (int m = 1; m <= 4; m <<= 1) {
    const float ov1 = __shfl_xor(v1, m);
    const int   oi1 = __shfl_xor(i1, m);
    const float ov2 = __shfl_xor(v2, m);
    const int   oi2 = __shfl_xor(i2, m);
    const bool o_beats = (ov1 > v1) || (ov1 == v1 && oi1 < i1);
    if (o_beats) {
      const bool v1_beats_o2 = (v1 > ov2) || (v1 == ov2 && i1 < oi2);
      v2 = v1_beats_o2 ? v1 : ov2;
      i2 = v1_beats_o2 ? i1 : oi2;
      v1 = ov1;
      i1 = oi1;
    } else {
      const bool o1_beats_v2 = (ov1 > v2) || (ov1 == v2 && oi1 < i2);
      if (o1_beats_v2) { v2 = ov1; i2 = oi1; }
    }
  }

  if (h == 0) {
    const float ex = expf((v2 - v1) * (1.0f / 3.0f));  // <= 1
    const float w1 = 1.0f / (1.0f + ex);
    const size_t o = (size_t)tok * 2;
    *(float2*)(out + o) = make_float2((float)i1, (float)i2);
    *(float2*)(out + (size_t)BB * SS * 2 + o) = make_float2(w1, ex * w1);
  }
}

extern "C" void kernel_launch(void* const* d_in, const int* in_sizes, int n_in,
                              void* d_out, int out_size, void* d_ws, size_t ws_size,
                              hipStream_t stream) {
  const float* x     = (const float*)d_in[0];
  const float* proto = (const float*)d_in[1];
  // d_in[2] = attn_mask: unused by the reference output path.
  float* out   = (float*)d_out;
  float* ptt   = (float*)d_ws;                             // 256 KiB ptt[d][e]
  float* pdots = (float*)((char*)d_ws + (512 << 10));      // 2 x 4 MiB halves
  float* qpart = (float*)((char*)d_ws + (512 << 10) + (8 << 20));  // 2 x 64 KiB

  repack_proto<<<dim3(256), dim3(256), 0, stream>>>(proto, ptt);
  router_dots<<<dim3(512), dim3(512), 0, stream>>>(x, ptt, pdots, qpart);
  router_top2<<<dim3(512), dim3(256), 0, stream>>>(pdots, qpart, out);
}

// Round 13
// 123.650 us; speedup vs baseline: 3.9278x; 1.1822x over previous
//
#include <hip/hip_runtime.h>
#include <math.h>

// ClownSelector R22 (= R21 resubmit): fuse top2 into dots via LOCAL halo
// recompute (no grid sync). R21's bench never ran -- "MI355X container
// failed twice" is an acquire/infra failure (no pytest, no timing block).
// Re-audited for hang/fault candidates: bounds exact-in-bounds (proto
// prefetch max index 65535; x row offset max 1023), all __syncthreads at
// block scope, LDS aliasing (B0/B1 in dead xt/pt; T written post-barrier;
// w1 halo rows [0..135] disjoint from w0 T rows [136..4487]), s0==0 clamp
// reproduces replicate-token-0 exactly. No defect found; resubmitting.
//
// Design (from R20/R18 ledger): rd floor ~27us (DS-bound); all more-waves
// paths closed (1024thr = hard 64-VGPR cap; split-K = L3 blowup). Dominant
// remaining cost = top2 dispatch + its launch overhead (~25-30us + fixed).
// Eliminate it in-block: the cross-block dep is only 2 halo rows (s0-2,
// s0-1) -> recompute locally (+8 ds_read_b32 + 16 fmac per chunk, ~+3us),
// then window/top2/softmax straight from an LDS table T[66][68].
// launch_bounds(512,1): VGPR cap 256; only 2 waves/SIMD resident anyway.
// Canary: WRITE_SIZE ~0.3MB; >>10MB = spill => revert to R18+R17 pair.

#define BB 8
#define SS 2048
#define DD 1024
#define EE 64
#define EPSV 1e-8f

#define FMA4(A, s, P) \
  A.x += (s) * (P).x; A.y += (s) * (P).y; A.z += (s) * (P).z; A.w += (s) * (P).w;

#define SUMSQ4(v) ((v).x * (v).x + (v).y * (v).y + (v).z * (v).z + (v).w * (v).w)

// ---- K0: proto[e][d] -> ptt[d][e] -----------------------------------------
__global__ __launch_bounds__(256) void repack_proto(
    const float* __restrict__ proto, float* __restrict__ ptt) {
  const int gid = blockIdx.x * 256 + threadIdx.x;  // 0..65535
  const int d = gid >> 6;
  const int e = gid & 63;
  ptt[gid] = proto[(size_t)e * DD + d];
}

// ---- fused: dots + window-3 + top-2 + softmax ------------------------------
// SMEM layout (floats):
//   [    0 ..  4351]  xt: 8 waves x [8 k][68 pad]   (single-buffered)
//   [ 4352 ..  8447]  pt: 8 waves x [8 k][64 e]     (single-buffered)
//   [ 8704 ..  9215]  nq: [8 wave][64 tok]
//   [ 9216 .. 10239]  hp: [8 wave][2 halo][64 e]
//   [10240 .. 10255]  hq: [8 wave][2 halo] sumsq partials
// Tree aliases B0=[0..4352), B1=[4352..8704) (dead xt/pt).
// Final table T[66][68] aliases [0..4488) (written after B0/B1 are dead).
__global__ __launch_bounds__(512, 1) void fused_router(
    const float* __restrict__ x, const float* __restrict__ ptt,
    float* __restrict__ out) {
  __shared__ float SMEM[10256];

  const int tid  = threadIdx.x;
  const int lane = tid & 63;
  const int w    = __builtin_amdgcn_readfirstlane(tid >> 6);  // 0..7
  const int eg   = lane & 7;   // experts [eg*8, +8)
  const int tg   = lane >> 3;  // tokens  [tg*8, +8)
  const int b    = blockIdx.x >> 5;          // 8 batches
  const int s0   = (blockIdx.x & 31) * 64;   // 64 tokens per block

  float* xtw = SMEM + w * 544;           // [8][68]
  float* ptw = SMEM + 4352 + w * 512;    // [8][64]
  float* nqp = SMEM + 8704;              // [8][64]
  float* hpp = SMEM + 9216;              // [8][2][64]
  float* hqq = SMEM + 10240;             // [8][2]

  const int kbase = w * 128;   // this wave's k-slice (128 wide)
  const float* xsrow = x + ((size_t)b * SS + s0 + lane) * DD + kbase;
  const float* psrow = ptt + (size_t)kbase * EE + lane * 4;

  // halo source rows (same batch); s0==0 clamps to row 0 (values unused then)
  const int g0 = (s0 >= 2) ? s0 - 2 : 0;
  const int g1 = (s0 >= 1) ? s0 - 1 : 0;
  const float* xh0 = x + ((size_t)b * SS + g0) * DD + kbase;
  const float* xh1 = x + ((size_t)b * SS + g1) * DD + kbase;

  float4 accA0[4], accA1[4], accB0[4], accB1[4];
#pragma unroll
  for (int i = 0; i < 4; ++i) {
    accA0[i] = make_float4(0.f, 0.f, 0.f, 0.f);
    accA1[i] = make_float4(0.f, 0.f, 0.f, 0.f);
    accB0[i] = make_float4(0.f, 0.f, 0.f, 0.f);
    accB1[i] = make_float4(0.f, 0.f, 0.f, 0.f);
  }
  float q = 0.0f;
  float ha0 = 0.0f, ha1 = 0.0f;   // halo dot partials (lane = expert)
  float hs0 = 0.0f, hs1 = 0.0f;   // halo sumsq partials (wave-uniform)

  // ---- prologue: stage chunk 0 (x transposed + proto) ----
  {
    const float4 v0 = *(const float4*)(xsrow);
    const float4 v1 = *(const float4*)(xsrow + 4);
    const float4 r0 = *(const float4*)(psrow);
    const float4 r1 = *(const float4*)(psrow + 256);
    q += SUMSQ4(v0) + SUMSQ4(v1);
    float* d = xtw + lane;
    d[0]   = v0.x; d[68]  = v0.y; d[136] = v0.z; d[204] = v0.w;
    d[272] = v1.x; d[340] = v1.y; d[408] = v1.z; d[476] = v1.w;
    *(float4*)(ptw + lane * 4)       = r0;
    *(float4*)(ptw + 256 + lane * 4) = r1;
  }

  const float* xc = xtw + tg * 8;   // + kk*68
  const float* pc = ptw + eg * 8;   // + kk*64

  for (int c = 0; c < 16; ++c) {   // 16 chunks x 8 k = 128 k per wave
    // ---- prefetch next chunk (consumed after the k-loop) ----
    float4 v0, v1, r0, r1;
    if (c + 1 < 16) {
      v0 = *(const float4*)(xsrow + (c + 1) * 8);
      v1 = *(const float4*)(xsrow + (c + 1) * 8 + 4);
      r0 = *(const float4*)(psrow + (c + 1) * 512);
      r1 = *(const float4*)(psrow + (c + 1) * 512 + 256);
    }
    // halo x for this chunk (wave-uniform addresses)
    float h0v[8], h1v[8];
#pragma unroll
    for (int kk = 0; kk < 8; ++kk) {
      h0v[kk] = xh0[c * 8 + kk];
      h1v[kk] = xh1[c * 8 + kk];
    }
    // ---- 8 k-steps: 2 b128 (x, 8 tok) + 2 b128 (proto, 8 exp) + 64 fmac ----
#pragma unroll
    for (int kk = 0; kk < 8; ++kk) {
      const float4 xfA = *(const float4*)(xc + kk * 68);
      const float4 xfB = *(const float4*)(xc + kk * 68 + 4);
      const float4 p0  = *(const float4*)(pc + kk * 64);
      const float4 p1  = *(const float4*)(pc + kk * 64 + 4);
      FMA4(accA0[0], xfA.x, p0) FMA4(accA1[0], xfA.x, p1)
      FMA4(accA0[1], xfA.y, p0) FMA4(accA1[1], xfA.y, p1)
      FMA4(accA0[2], xfA.z, p0) FMA4(accA1[2], xfA.z, p1)
      FMA4(accA0[3], xfA.w, p0) FMA4(accA1[3], xfA.w, p1)
      FMA4(accB0[0], xfB.x, p0) FMA4(accB1[0], xfB.x, p1)
      FMA4(accB0[1], xfB.y, p0) FMA4(accB1[1], xfB.y, p1)
      FMA4(accB0[2], xfB.z, p0) FMA4(accB1[2], xfB.z, p1)
      FMA4(accB0[3], xfB.w, p0) FMA4(accB1[3], xfB.w, p1)
    }
    // ---- halo rows vs this proto chunk (lane = expert; reads BEFORE the
    //      staging writes below -> wave-private DS in-order keeps it safe) ---
#pragma unroll
    for (int kk = 0; kk < 8; ++kk) {
      const float pv = ptw[kk * 64 + lane];
      ha0 += h0v[kk] * pv;
      ha1 += h1v[kk] * pv;
      hs0 += h0v[kk] * h0v[kk];
      hs1 += h1v[kk] * h1v[kk];
    }
    // ---- stage prefetched chunk (same buffers; wave-private DS in-order) ----
    if (c + 1 < 16) {
      q += SUMSQ4(v0) + SUMSQ4(v1);
      float* d = xtw + lane;
      d[0]   = v0.x; d[68]  = v0.y; d[136] = v0.z; d[204] = v0.w;
      d[272] = v1.x; d[340] = v1.y; d[408] = v1.z; d[476] = v1.w;
      *(float4*)(ptw + lane * 4)       = r0;
      *(float4*)(ptw + 256 + lane * 4) = r1;
    }
  }

  // publish per-wave partials (covered by the tree's first barrier)
  nqp[w * 64 + lane] = q;
  hpp[w * 128 + lane]      = ha0;
  hpp[w * 128 + 64 + lane] = ha1;
  if (lane == 0) { hqq[w * 2] = hs0; hqq[w * 2 + 1] = hs1; }

  // tree buffers alias the (now dead) xt/pt regions: [64][68] each
  float* B0 = SMEM;
  float* B1 = SMEM + 4352;

#define WRB(R)                                                        \
  { _Pragma("unroll") for (int i = 0; i < 4; ++i) {                   \
      float* pA_ = (R) + (tg * 8 + i) * 68 + eg * 8;                  \
      float* pB_ = (R) + (tg * 8 + 4 + i) * 68 + eg * 8;              \
      *(float4*)(pA_)     = accA0[i];                                 \
      *(float4*)(pA_ + 4) = accA1[i];                                 \
      *(float4*)(pB_)     = accB0[i];                                 \
      *(float4*)(pB_ + 4) = accB1[i]; } }
#define ADDB(R)                                                       \
  { _Pragma("unroll") for (int i = 0; i < 4; ++i) {                   \
      const float* pA_ = (R) + (tg * 8 + i) * 68 + eg * 8;            \
      const float* pB_ = (R) + (tg * 8 + 4 + i) * 68 + eg * 8;        \
      const float4 tA0 = *(const float4*)(pA_);                       \
      const float4 tA1 = *(const float4*)(pA_ + 4);                   \
      const float4 tB0 = *(const float4*)(pB_);                       \
      const float4 tB1 = *(const float4*)(pB_ + 4);                   \
      accA0[i].x += tA0.x; accA0[i].y += tA0.y;                       \
      accA0[i].z += tA0.z; accA0[i].w += tA0.w;                       \
      accA1[i].x += tA1.x; accA1[i].y += tA1.y;                       \
      accA1[i].z += tA1.z; accA1[i].w += tA1.w;                       \
      accB0[i].x += tB0.x; accB0[i].y += tB0.y;                       \
      accB0[i].z += tB0.z; accB0[i].w += tB0.w;                       \
      accB1[i].x += tB1.x; accB1[i].y += tB1.y;                       \
      accB1[i].z += tB1.z; accB1[i].w += tB1.w; } }

  // deterministic tree over 8 waves (R13/R18's exact sequence)
  __syncthreads();
  if (w == 1) WRB(B0)
  if (w == 5) WRB(B1)
  __syncthreads();
  if (w == 0) ADDB(B0)
  if (w == 4) ADDB(B1)
  __syncthreads();
  if (w == 3) WRB(B0)
  if (w == 7) WRB(B1)
  __syncthreads();
  if (w == 2) ADDB(B0)
  if (w == 6) ADDB(B1)
  __syncthreads();
  if (w == 2) WRB(B0)
  if (w == 6) WRB(B1)
  __syncthreads();
  if (w == 0) ADDB(B0)
  if (w == 4) ADDB(B1)
  __syncthreads();
  if (w == 4) WRB(B0)
  __syncthreads();
  if (w == 0) ADDB(B0)
  __syncthreads();   // B0/B1 fully consumed -> T region writable

  // ---- build normalized table T[66][68] at SMEM[0..4488) ----
  if (w == 0) {
#pragma unroll
    for (int i = 0; i < 4; ++i) {
      const int rA = tg * 8 + i;
      const int rB = rA + 4;
      float qsA = 0.0f, qsB = 0.0f;
#pragma unroll
      for (int ww = 0; ww < 8; ++ww) {
        qsA += nqp[ww * 64 + rA];
        qsB += nqp[ww * 64 + rB];
      }
      const float invA = 1.0f / fmaxf(sqrtf(qsA), EPSV);
      const float invB = 1.0f / fmaxf(sqrtf(qsB), EPSV);
      float4 oA0 = accA0[i], oA1 = accA1[i], oB0 = accB0[i], oB1 = accB1[i];
      oA0.x *= invA; oA0.y *= invA; oA0.z *= invA; oA0.w *= invA;
      oA1.x *= invA; oA1.y *= invA; oA1.z *= invA; oA1.w *= invA;
      oB0.x *= invB; oB0.y *= invB; oB0.z *= invB; oB0.w *= invB;
      oB1.x *= invB; oB1.y *= invB; oB1.z *= invB; oB1.w *= invB;
      float* TA = SMEM + (2 + rA) * 68 + eg * 8;
      float* TB = SMEM + (2 + rB) * 68 + eg * 8;
      *(float4*)(TA)     = oA0;
      *(float4*)(TA + 4) = oA1;
      *(float4*)(TB)     = oB0;
      *(float4*)(TB + 4) = oB1;
    }
  }
  if (w == 1) {   // halo rows 0,1 (lane = expert)
    float d0 = 0.f, d1 = 0.f, q0 = 0.f, q1 = 0.f;
#pragma unroll
    for (int ww = 0; ww < 8; ++ww) {
      d0 += hpp[ww * 128 + lane];
      d1 += hpp[ww * 128 + 64 + lane];
      q0 += hqq[ww * 2];
      q1 += hqq[ww * 2 + 1];
    }
    SMEM[lane]      = d0 * (1.0f / fmaxf(sqrtf(q0), EPSV));
    SMEM[68 + lane] = d1 * (1.0f / fmaxf(sqrtf(q1), EPSV));
  }
  __syncthreads();   // T ready

  // ---- window-3 + top-2 + softmax (R17-verified math, from LDS) ----
#define T2UP(s, ei)                                            \
  if ((s) > v1) { v2 = v1; i2 = i1; v1 = (s); i1 = (ei); }     \
  else if ((s) > v2) { v2 = (s); i2 = (ei); }

  {
    const int t   = tid >> 3;   // block-local token 0..63
    const int oct = tid & 7;    // 8 experts each
    int ra = t, rb = t + 1;     // T rows for sl-2, sl-1 (T[r] = dots[s0-2+r])
    if (s0 == 0) {              // replicate token 0 (old clamp semantics)
      ra = (t < 2) ? 2 : t;
      rb = (t == 0) ? 2 : t + 1;
    }
    const float* Ta = SMEM + ra * 68 + oct * 8;
    const float* Tb = SMEM + rb * 68 + oct * 8;
    const float* Tc = SMEM + (t + 2) * 68 + oct * 8;

    float v1 = -INFINITY, v2 = -INFINITY;
    int i1 = 0, i2 = 0;
#pragma unroll
    for (int qd = 0; qd < 2; ++qd) {
      const float4 a = *(const float4*)(Ta + qd * 4);
      const float4 c = *(const float4*)(Tb + qd * 4);
      const float4 e = *(const float4*)(Tc + qd * 4);
      const int e0 = oct * 8 + qd * 4;
      float s;
      s = a.x + c.x + e.x; T2UP(s, e0 + 0)
      s = a.y + c.y + e.y; T2UP(s, e0 + 1)
      s = a.z + c.z + e.z; T2UP(s, e0 + 2)
      s = a.w + c.w + e.w; T2UP(s, e0 + 3)
    }

    // merge the 8 octs (partners lane^1, lane^2, lane^4); tie -> lower index
#pragma unroll
    for (int m = 1; m <= 4; m <<= 1) {
      const float ov1 = __shfl_xor(v1, m);
      const int   oi1 = __shfl_xor(i1, m);
      const float ov2 = __shfl_xor(v2, m);
      const int   oi2 = __shfl_xor(i2, m);
      const bool o_beats = (ov1 > v1) || (ov1 == v1 && oi1 < i1);
      if (o_beats) {
        const bool v1_beats_o2 = (v1 > ov2) || (v1 == ov2 && i1 < oi2);
        v2 = v1_beats_o2 ? v1 : ov2;
        i2 = v1_beats_o2 ? i1 : oi2;
        v1 = ov1;
        i1 = oi1;
      } else {
        const bool o1_beats_v2 = (ov1 > v2) || (ov1 == v2 && oi1 < i2);
        if (o1_beats_v2) { v2 = ov1; i2 = oi1; }
      }
    }

    if (oct == 0) {
      const float ex = expf((v2 - v1) * (1.0f / 3.0f));  // <= 1
      const float w1 = 1.0f / (1.0f + ex);
      const size_t gt = (size_t)b * SS + s0 + t;
      const size_t o = gt * 2;
      *(float2*)(out + o) = make_float2((float)i1, (float)i2);
      *(float2*)(out + (size_t)BB * SS * 2 + o) = make_float2(w1, ex * w1);
    }
  }
}

extern "C" void kernel_launch(void* const* d_in, const int* in_sizes, int n_in,
                              void* d_out, int out_size, void* d_ws, size_t ws_size,
                              hipStream_t stream) {
  const float* x     = (const float*)d_in[0];
  const float* proto = (const float*)d_in[1];
  // d_in[2] = attn_mask: unused by the reference output path.
  float* out = (float*)d_out;
  float* ptt = (float*)d_ws;   // 256 KiB ptt[d][e]

  repack_proto<<<dim3(256), dim3(256), 0, stream>>>(proto, ptt);
  fused_router<<<dim3(256), dim3(512), 0, stream>>>(x, ptt, out);
}